// Round 5
// baseline (1489.952 us; speedup 1.0000x reference)
//
#include <hip/hip_runtime.h>
#include <hip/hip_bf16.h>
#include <math.h>
#include <stdint.h>

// Problem constants
constexpr int N_ROWS = 32768;
constexpr int K_DIM  = 4096;
constexpr int R_DIM  = 256;
constexpr int KP     = 3 * R_DIM;   // 768: split-K' for [hi|hi|lo] x [hi|lo|hi]

typedef __bf16 bf16x8 __attribute__((ext_vector_type(8)));
typedef float  f32x4  __attribute__((ext_vector_type(4)));
typedef unsigned short u16x8 __attribute__((ext_vector_type(8)));
typedef unsigned short u16x4 __attribute__((ext_vector_type(4)));

// ---- bf16 helpers (round-to-nearest-even) ----
__device__ __forceinline__ unsigned short f2bf(float x) {
    unsigned u = __float_as_uint(x);
    u += 0x7fffu + ((u >> 16) & 1u);
    return (unsigned short)(u >> 16);
}
__device__ __forceinline__ float bf2f(unsigned short h) {
    return __uint_as_float((unsigned)h << 16);
}

// ---- async global->LDS, 16B/lane, LDS dest = wave-uniform base + lane*16
__device__ __forceinline__ void gl2lds16(const void* gptr, void* lptr) {
    __builtin_amdgcn_global_load_lds(
        (const __attribute__((address_space(1))) unsigned int*)gptr,
        (__attribute__((address_space(3))) unsigned int*)lptr,
        16, 0, 0);
}

// ===========================================================================
// K2: MFMA NT GEMM: C[m,n] = sum_k A[m,k]*B[n,k], bf16 in, fp32 out.
// 128x128 tile, BK=32, 4 waves (2x2 of 64x64), 16x16x32 MFMA.
// Grid: x = N-tile (fast-varying -> A-strip L2 reuse), y = M-tile.
// ===========================================================================
__global__ __launch_bounds__(256)
void gemm_mfma_nt(const unsigned short* __restrict__ A,
                  const unsigned short* __restrict__ B,
                  float* __restrict__ C, int M, int N, int Kc)
{
    __shared__ __align__(16) unsigned short As[128 * 32];
    __shared__ __align__(16) unsigned short Bs[128 * 32];

    const int tid  = threadIdx.x;
    const int wave = tid >> 6, lane = tid & 63;
    const int wm = wave >> 1, wn = wave & 1;
    const long m0 = (long)blockIdx.y * 128;
    const long n0 = (long)blockIdx.x * 128;

    f32x4 acc[4][4] = {};

    const int srow  = lane >> 2;
    const int skoff = (lane & 3) * 8;
    const int c0 = wave, c1 = wave + 4;
    const int kq = (lane >> 4) * 8;
    const int mr = lane & 15;

    for (int k0 = 0; k0 < Kc; k0 += 32) {
        gl2lds16(A + (m0 + c0 * 16 + srow) * (long)Kc + k0 + skoff, &As[c0 * 512]);
        gl2lds16(A + (m0 + c1 * 16 + srow) * (long)Kc + k0 + skoff, &As[c1 * 512]);
        gl2lds16(B + (n0 + c0 * 16 + srow) * (long)Kc + k0 + skoff, &Bs[c0 * 512]);
        gl2lds16(B + (n0 + c1 * 16 + srow) * (long)Kc + k0 + skoff, &Bs[c1 * 512]);
        __syncthreads();

        bf16x8 af[4], bfr[4];
#pragma unroll
        for (int t = 0; t < 4; ++t) {
            af[t]  = *(const bf16x8*)&As[(wm * 64 + t * 16 + mr) * 32 + kq];
            bfr[t] = *(const bf16x8*)&Bs[(wn * 64 + t * 16 + mr) * 32 + kq];
        }
#pragma unroll
        for (int i = 0; i < 4; ++i)
#pragma unroll
            for (int j = 0; j < 4; ++j)
                acc[i][j] = __builtin_amdgcn_mfma_f32_16x16x32_bf16(
                    af[i], bfr[j], acc[i][j], 0, 0, 0);
        __syncthreads();
    }

    const int col = lane & 15, rquad = (lane >> 4) * 4;
#pragma unroll
    for (int i = 0; i < 4; ++i) {
        const long mrow = m0 + wm * 64 + i * 16 + rquad;
#pragma unroll
        for (int j = 0; j < 4; ++j) {
            float* p = C + mrow * (long)N + n0 + wn * 64 + j * 16 + col;
#pragma unroll
            for (int r = 0; r < 4; ++r) p[(long)r * N] = acc[i][j][r];
        }
    }
}

// ===========================================================================
// K1 fused: P = H @ W_I (fp32 VALU GEMM) with split epilogue -> Ap.
// ===========================================================================
__global__ __launch_bounds__(256)
void k1_ap(const float* __restrict__ A, const float* __restrict__ B,
           unsigned short* __restrict__ Ap)
{
    __shared__ __align__(16) float Asl[16][132];
    __shared__ __align__(16) float Bsl[16][132];
    const int tid = threadIdx.x;
    const int tx = tid & 15, ty = tid >> 4;
    const long m0 = (long)blockIdx.x * 128;
    const long n0 = (long)blockIdx.y * 128;
    const int Kc = R_DIM, N = R_DIM;

    float acc[8][8];
#pragma unroll
    for (int i = 0; i < 8; ++i)
#pragma unroll
        for (int j = 0; j < 8; ++j) acc[i][j] = 0.f;

    for (int k0 = 0; k0 < Kc; k0 += 16) {
#pragma unroll
        for (int q = 0; q < 2; ++q) {
            int fi = tid + 256 * q, row = fi >> 2, col = (fi & 3) * 4;
            float4 v = *(const float4*)(A + (m0 + row) * (long)Kc + k0 + col);
            Asl[col + 0][row] = v.x; Asl[col + 1][row] = v.y;
            Asl[col + 2][row] = v.z; Asl[col + 3][row] = v.w;
        }
#pragma unroll
        for (int q = 0; q < 2; ++q) {
            int fi = tid + 256 * q, row = fi >> 5, col = (fi & 31) * 4;
            float4 v = *(const float4*)(B + (k0 + row) * (long)N + n0 + col);
            *(float4*)&Bsl[row][col] = v;
        }
        __syncthreads();
#pragma unroll
        for (int kk = 0; kk < 16; ++kk) {
            float a[8], b[8];
            *(float4*)&a[0] = *(const float4*)&Asl[kk][ty * 8];
            *(float4*)&a[4] = *(const float4*)&Asl[kk][ty * 8 + 4];
            *(float4*)&b[0] = *(const float4*)&Bsl[kk][tx * 8];
            *(float4*)&b[4] = *(const float4*)&Bsl[kk][tx * 8 + 4];
#pragma unroll
            for (int i = 0; i < 8; ++i)
#pragma unroll
                for (int j = 0; j < 8; ++j)
                    acc[i][j] = fmaf(a[i], b[j], acc[i][j]);
        }
        __syncthreads();
    }
#pragma unroll
    for (int i = 0; i < 8; ++i) {
        const long row = m0 + ty * 8 + i;
        u16x8 hi8, lo8;
#pragma unroll
        for (int j = 0; j < 8; ++j) {
            const unsigned short h = f2bf(acc[i][j]);
            hi8[j] = h;
            lo8[j] = f2bf(acc[i][j] - bf2f(h));
        }
        unsigned short* p = Ap + row * KP + n0 + tx * 8;
        *(u16x8*)(p)              = hi8;
        *(u16x8*)(p + R_DIM)      = hi8;
        *(u16x8*)(p + 2 * R_DIM)  = lo8;
    }
}

// ===========================================================================
// Tail fused v2: per 32-row strip —
//  phase 1: stream M once, online per-row (max, sum-exp).
//  phase 2: software-pipelined; A-fragments loaded DIRECTLY from global M in
//  MFMA A-layout (lane: rows lane&15 / +16, k = (lane>>4)*8..+7), exp'd and
//  packed in-register (no LDS round-trip for A). Wave 0 writes fp32 A back.
//  LT staged via double-buffered global_load_lds.
// ===========================================================================
__global__ __launch_bounds__(256)
void fused_saw2(float* __restrict__ Mio, const unsigned short* __restrict__ LT,
                float* __restrict__ C)
{
    __shared__ __align__(16) unsigned short Bs[2][256 * 32];
    __shared__ float sm[32][8];
    __shared__ float ss[32][8];
    __shared__ float rowm[32];
    __shared__ float rowiv[32];

    const int tid = threadIdx.x, wave = tid >> 6, lane = tid & 63;
    const long m0 = (long)blockIdx.x * 32;

    // ---- phase 1: online (max, sum-exp); thread owns row tid>>3, 512 elems
    const int arow = tid >> 3, acol = (tid & 7) * 4;
    {
        const float* rp = Mio + (m0 + arow) * (long)K_DIM + acol;
        float m = -3.4e38f, s = 0.f;
#pragma unroll 4
        for (int q = 0; q < 128; ++q) {
            float4 v = *(const float4*)(rp + 32 * q);
            float m4 = fmaxf(fmaxf(v.x, v.y), fmaxf(v.z, v.w));
            if (m4 > m) { s *= __expf(m - m4); m = m4; }
            s += __expf(v.x - m) + __expf(v.y - m)
               + __expf(v.z - m) + __expf(v.w - m);
        }
        sm[arow][tid & 7] = m;
        ss[arow][tid & 7] = s;
    }
    __syncthreads();
    if ((tid & 7) == 0) {
        float m = sm[arow][0];
#pragma unroll
        for (int t = 1; t < 8; ++t) m = fmaxf(m, sm[arow][t]);
        float S = 0.f;
#pragma unroll
        for (int t = 0; t < 8; ++t) S += ss[arow][t] * __expf(sm[arow][t] - m);
        rowm[arow] = m;
        rowiv[arow] = 1.f / S;
    }
    __syncthreads();

    // ---- phase 2 ----
    const int fr = lane & 15;            // fragment row within 16
    const int kq = (lane >> 4) * 8;      // fragment k-offset 0,8,16,24
    const float rm0 = rowm[fr],      ri0 = rowiv[fr];
    const float rm1 = rowm[fr + 16], ri1 = rowiv[fr + 16];

    const int srow = lane >> 2, skoff = (lane & 3) * 8;

    float* R0 = Mio + (m0 + fr) * (long)K_DIM + kq;        // row fr
    float* R1 = R0 + 16 * (long)K_DIM;                     // row fr+16

    auto stageB = [&](int buf, int k0) {
#pragma unroll
        for (int c4 = 0; c4 < 4; ++c4) {
            const int c = wave * 4 + c4;
            gl2lds16(LT + (c * 16 + srow) * (long)K_DIM + k0 + skoff,
                     &Bs[buf][c * 512]);
        }
    };

    f32x4 acc[2][4] = {};
    float4 va00, va01, va10, va11;
    float4 vn00 = {}, vn01 = {}, vn10 = {}, vn11 = {};

    constexpr int NIT = K_DIM / 32;
    int cb = 0;
    stageB(0, 0);
    va00 = *(const float4*)(R0);     va01 = *(const float4*)(R0 + 4);
    va10 = *(const float4*)(R1);     va11 = *(const float4*)(R1 + 4);
    __syncthreads();

#pragma unroll 1
    for (int it = 0; it < NIT; ++it) {
        const int k0 = it * 32;
        if (it + 1 < NIT) {
            stageB(cb ^ 1, k0 + 32);
            vn00 = *(const float4*)(R0 + k0 + 32);
            vn01 = *(const float4*)(R0 + k0 + 36);
            vn10 = *(const float4*)(R1 + k0 + 32);
            vn11 = *(const float4*)(R1 + k0 + 36);
        }

        // exp-normalize in registers
        float x0[8] = {va00.x, va00.y, va00.z, va00.w,
                       va01.x, va01.y, va01.z, va01.w};
        float x1[8] = {va10.x, va10.y, va10.z, va10.w,
                       va11.x, va11.y, va11.z, va11.w};
        float e0[8], e1[8];
        u16x8 p0, p1;
#pragma unroll
        for (int j = 0; j < 8; ++j) {
            e0[j] = __expf(x0[j] - rm0) * ri0;  p0[j] = f2bf(e0[j]);
            e1[j] = __expf(x1[j] - rm1) * ri1;  p1[j] = f2bf(e1[j]);
        }
        // write fp32 A back (wave 0 only — all waves hold identical copies)
        if (wave == 0) {
            *(float4*)(R0 + k0)     = make_float4(e0[0], e0[1], e0[2], e0[3]);
            *(float4*)(R0 + k0 + 4) = make_float4(e0[4], e0[5], e0[6], e0[7]);
            *(float4*)(R1 + k0)     = make_float4(e1[0], e1[1], e1[2], e1[3]);
            *(float4*)(R1 + k0 + 4) = make_float4(e1[4], e1[5], e1[6], e1[7]);
        }

        const bf16x8 af0 = __builtin_bit_cast(bf16x8, p0);
        const bf16x8 af1 = __builtin_bit_cast(bf16x8, p1);
        bf16x8 bfr[4];
#pragma unroll
        for (int j = 0; j < 4; ++j)
            bfr[j] = *(const bf16x8*)&Bs[cb][(wave * 64 + j * 16 + fr) * 32 + kq];
#pragma unroll
        for (int j = 0; j < 4; ++j) {
            acc[0][j] = __builtin_amdgcn_mfma_f32_16x16x32_bf16(
                af0, bfr[j], acc[0][j], 0, 0, 0);
            acc[1][j] = __builtin_amdgcn_mfma_f32_16x16x32_bf16(
                af1, bfr[j], acc[1][j], 0, 0, 0);
        }
        __syncthreads();
        cb ^= 1;
        va00 = vn00; va01 = vn01; va10 = vn10; va11 = vn11;
    }

    const int col = lane & 15, rq = (lane >> 4) * 4;
#pragma unroll
    for (int i = 0; i < 2; ++i)
#pragma unroll
        for (int j = 0; j < 4; ++j)
#pragma unroll
            for (int r = 0; r < 4; ++r)
                C[(m0 + i * 16 + rq + r) * (long)R_DIM + wave * 64 + j * 16 + col]
                    = acc[i][j][r];
}

// ===========================================================================
// Prep kernels (L-derived operands)
// ===========================================================================
__global__ __launch_bounds__(256)
void prep_B(const float* __restrict__ L, unsigned short* __restrict__ Bp)
{
    const long i = (long)blockIdx.x * 256 + threadIdx.x;
    const long k = i >> 8; const int r = (int)(i & 255);
    const float x = L[i];
    const unsigned short hi = f2bf(x);
    const unsigned short lo = f2bf(x - bf2f(hi));
    unsigned short* row = Bp + k * KP;
    row[r] = hi; row[R_DIM + r] = lo; row[2 * R_DIM + r] = hi;
}

// LDS-tile transpose: LT[r][k] = bf16(L[k][r]); coalesced both sides.
__global__ __launch_bounds__(256)
void prep_LT(const float* __restrict__ L, unsigned short* __restrict__ LT)
{
    __shared__ unsigned short t[64][66];
    const int k0 = blockIdx.x * 64;
    const int r0 = blockIdx.y * 64;
    const int tid = threadIdx.x;
#pragma unroll
    for (int q = 0; q < 16; ++q) {
        const int e = q * 256 + tid;
        const int kk = e >> 6, rr = e & 63;
        t[rr][kk] = f2bf(L[(long)(k0 + kk) * R_DIM + r0 + rr]);
    }
    __syncthreads();
#pragma unroll
    for (int q = 0; q < 16; ++q) {
        const int e = q * 256 + tid;
        const int rr = e >> 6, kk = e & 63;
        LT[(long)(r0 + rr) * K_DIM + k0 + kk] = t[rr][kk];
    }
}

// ===========================================================================
// Fallback kernels (fp32 path, no workspace)
// ===========================================================================
template<bool BT>
__global__ __launch_bounds__(256)
void gemm128(const float* __restrict__ A, const float* __restrict__ B,
             float* __restrict__ C, int M, int N, int Kc)
{
    __shared__ __align__(16) float Asl[16][132];
    __shared__ __align__(16) float Bsl[16][132];
    const int tid = threadIdx.x;
    const int tx = tid & 15, ty = tid >> 4;
    const long m0 = (long)blockIdx.x * 128;
    const long n0 = (long)blockIdx.y * 128;
    float acc[8][8];
#pragma unroll
    for (int i = 0; i < 8; ++i)
#pragma unroll
        for (int j = 0; j < 8; ++j) acc[i][j] = 0.f;
    for (int k0 = 0; k0 < Kc; k0 += 16) {
#pragma unroll
        for (int q = 0; q < 2; ++q) {
            int fi = tid + 256 * q, row = fi >> 2, col = (fi & 3) * 4;
            float4 v = *(const float4*)(A + (m0 + row) * (long)Kc + k0 + col);
            Asl[col + 0][row] = v.x; Asl[col + 1][row] = v.y;
            Asl[col + 2][row] = v.z; Asl[col + 3][row] = v.w;
        }
        if (BT) {
#pragma unroll
            for (int q = 0; q < 2; ++q) {
                int fi = tid + 256 * q, row = fi >> 2, col = (fi & 3) * 4;
                float4 v = *(const float4*)(B + (n0 + row) * (long)Kc + k0 + col);
                Bsl[col + 0][row] = v.x; Bsl[col + 1][row] = v.y;
                Bsl[col + 2][row] = v.z; Bsl[col + 3][row] = v.w;
            }
        } else {
#pragma unroll
            for (int q = 0; q < 2; ++q) {
                int fi = tid + 256 * q, row = fi >> 5, col = (fi & 31) * 4;
                float4 v = *(const float4*)(B + (k0 + row) * (long)N + n0 + col);
                *(float4*)&Bsl[row][col] = v;
            }
        }
        __syncthreads();
#pragma unroll
        for (int kk = 0; kk < 16; ++kk) {
            float a[8], b[8];
            *(float4*)&a[0] = *(const float4*)&Asl[kk][ty * 8];
            *(float4*)&a[4] = *(const float4*)&Asl[kk][ty * 8 + 4];
            *(float4*)&b[0] = *(const float4*)&Bsl[kk][tx * 8];
            *(float4*)&b[4] = *(const float4*)&Bsl[kk][tx * 8 + 4];
#pragma unroll
            for (int i = 0; i < 8; ++i)
#pragma unroll
                for (int j = 0; j < 8; ++j)
                    acc[i][j] = fmaf(a[i], b[j], acc[i][j]);
        }
        __syncthreads();
    }
#pragma unroll
    for (int i = 0; i < 8; ++i) {
        float* p = C + (m0 + ty * 8 + i) * (long)N + n0 + tx * 8;
        *(float4*)p       = make_float4(acc[i][0], acc[i][1], acc[i][2], acc[i][3]);
        *(float4*)(p + 4) = make_float4(acc[i][4], acc[i][5], acc[i][6], acc[i][7]);
    }
}

__global__ __launch_bounds__(256)
void softmax_rows(float* __restrict__ Mio)
{
    const long n  = blockIdx.x;
    float* row    = Mio + n * (long)K_DIM;
    const int tid = threadIdx.x;
    float4 v[4];
    float lmax = -3.4e38f;
#pragma unroll
    for (int q = 0; q < 4; ++q) {
        v[q] = ((const float4*)row)[tid + 256 * q];
        lmax = fmaxf(lmax, fmaxf(fmaxf(v[q].x, v[q].y), fmaxf(v[q].z, v[q].w)));
    }
    __shared__ float redmax[4], redsum[4];
#pragma unroll
    for (int off = 32; off > 0; off >>= 1)
        lmax = fmaxf(lmax, __shfl_xor(lmax, off));
    if ((tid & 63) == 0) redmax[tid >> 6] = lmax;
    __syncthreads();
    const float gmax = fmaxf(fmaxf(redmax[0], redmax[1]), fmaxf(redmax[2], redmax[3]));
    float lsum = 0.f;
#pragma unroll
    for (int q = 0; q < 4; ++q) {
        v[q].x = __expf(v[q].x - gmax); v[q].y = __expf(v[q].y - gmax);
        v[q].z = __expf(v[q].z - gmax); v[q].w = __expf(v[q].w - gmax);
        lsum += v[q].x + v[q].y + v[q].z + v[q].w;
    }
#pragma unroll
    for (int off = 32; off > 0; off >>= 1)
        lsum += __shfl_xor(lsum, off);
    if ((tid & 63) == 0) redsum[tid >> 6] = lsum;
    __syncthreads();
    const float inv = 1.f / (redsum[0] + redsum[1] + redsum[2] + redsum[3]);
#pragma unroll
    for (int q = 0; q < 4; ++q) {
        v[q].x *= inv; v[q].y *= inv; v[q].z *= inv; v[q].w *= inv;
        ((float4*)row)[tid + 256 * q] = v[q];
    }
}

// ===========================================================================
extern "C" void kernel_launch(void* const* d_in, const int* in_sizes, int n_in,
                              void* d_out, int out_size, void* d_ws, size_t ws_size,
                              hipStream_t stream)
{
    const float* H  = (const float*)d_in[0];
    const float* L  = (const float*)d_in[1];
    const float* Wi = (const float*)d_in[2];

    float* Cout = (float*)d_out;                           // N x R
    float* Aout = (float*)d_out + (size_t)N_ROWS * R_DIM;  // N x K

    const size_t szAp = (size_t)N_ROWS * KP * 2;     // 48 MiB
    const size_t szBp = (size_t)K_DIM * KP * 2;      //  6 MiB
    const size_t szLT = (size_t)R_DIM * K_DIM * 2;   //  2 MiB

    if (ws_size >= szAp + szBp + szLT) {
        unsigned short* Ap = (unsigned short*)d_ws;
        unsigned short* Bp = (unsigned short*)((char*)d_ws + szAp);
        unsigned short* LT = (unsigned short*)((char*)d_ws + szAp + szBp);

        // K1 fused: P = H@W_I with split-epilogue -> Ap
        k1_ap<<<dim3(N_ROWS / 128, R_DIM / 128), 256, 0, stream>>>(H, Wi, Ap);
        // L-derived operands
        prep_B<<<dim3((K_DIM * R_DIM) / 256), 256, 0, stream>>>(L, Bp);
        prep_LT<<<dim3(K_DIM / 64, R_DIM / 64), 256, 0, stream>>>(L, LT);
        // K2: logits M
        gemm_mfma_nt<<<dim3(K_DIM / 128, N_ROWS / 128), 256, 0, stream>>>(
            Ap, Bp, Aout, N_ROWS, K_DIM, KP);
        // Tail fused v2: stats + softmax-in-place + C = A@L (pipelined)
        fused_saw2<<<dim3(N_ROWS / 32), 256, 0, stream>>>(Aout, LT, Cout);
    } else {
        gemm128<false><<<dim3(N_ROWS / 128, R_DIM / 128), 256, 0, stream>>>(
            H, Wi, Cout, N_ROWS, R_DIM, R_DIM);
        gemm128<true><<<dim3(N_ROWS / 128, K_DIM / 128), 256, 0, stream>>>(
            Cout, L, Aout, N_ROWS, K_DIM, R_DIM);
        softmax_rows<<<dim3(N_ROWS), 256, 0, stream>>>(Aout);
        gemm128<false><<<dim3(N_ROWS / 128, R_DIM / 128), 256, 0, stream>>>(
            Aout, L, Cout, N_ROWS, R_DIM, K_DIM);
    }
}

// Round 6
// 1342.558 us; speedup vs baseline: 1.1098x; 1.1098x over previous
//
#include <hip/hip_runtime.h>
#include <hip/hip_bf16.h>
#include <math.h>
#include <stdint.h>

// Problem constants
constexpr int N_ROWS = 32768;
constexpr int K_DIM  = 4096;
constexpr int R_DIM  = 256;
constexpr int KP     = 3 * R_DIM;   // 768: split-K' for [hi|hi|lo] x [hi|lo|hi]

typedef __bf16 bf16x8 __attribute__((ext_vector_type(8)));
typedef float  f32x4  __attribute__((ext_vector_type(4)));
typedef unsigned short u16x8 __attribute__((ext_vector_type(8)));
typedef unsigned short u16x4 __attribute__((ext_vector_type(4)));

// ---- bf16 helpers (round-to-nearest-even) ----
__device__ __forceinline__ unsigned short f2bf(float x) {
    unsigned u = __float_as_uint(x);
    u += 0x7fffu + ((u >> 16) & 1u);
    return (unsigned short)(u >> 16);
}
__device__ __forceinline__ float bf2f(unsigned short h) {
    return __uint_as_float((unsigned)h << 16);
}

// ---- async global->LDS, 16B/lane, LDS dest = wave-uniform base + lane*16
__device__ __forceinline__ void gl2lds16(const void* gptr, void* lptr) {
    __builtin_amdgcn_global_load_lds(
        (const __attribute__((address_space(1))) unsigned int*)gptr,
        (__attribute__((address_space(3))) unsigned int*)lptr,
        16, 0, 0);
}

// ===========================================================================
// K2: MFMA NT GEMM: C[m,n] = sum_k A[m,k]*B[n,k], bf16 in, fp32 out.
// 128x128 tile, BK=32, 4 waves (2x2 of 64x64), 16x16x32 MFMA.
// Grid: x = N-tile (fast-varying -> A-strip L2 reuse), y = M-tile.
// ===========================================================================
__global__ __launch_bounds__(256)
void gemm_mfma_nt(const unsigned short* __restrict__ A,
                  const unsigned short* __restrict__ B,
                  float* __restrict__ C, int M, int N, int Kc)
{
    __shared__ __align__(16) unsigned short As[128 * 32];
    __shared__ __align__(16) unsigned short Bs[128 * 32];

    const int tid  = threadIdx.x;
    const int wave = tid >> 6, lane = tid & 63;
    const int wm = wave >> 1, wn = wave & 1;
    const long m0 = (long)blockIdx.y * 128;
    const long n0 = (long)blockIdx.x * 128;

    f32x4 acc[4][4] = {};

    const int srow  = lane >> 2;
    const int skoff = (lane & 3) * 8;
    const int c0 = wave, c1 = wave + 4;
    const int kq = (lane >> 4) * 8;
    const int mr = lane & 15;

    for (int k0 = 0; k0 < Kc; k0 += 32) {
        gl2lds16(A + (m0 + c0 * 16 + srow) * (long)Kc + k0 + skoff, &As[c0 * 512]);
        gl2lds16(A + (m0 + c1 * 16 + srow) * (long)Kc + k0 + skoff, &As[c1 * 512]);
        gl2lds16(B + (n0 + c0 * 16 + srow) * (long)Kc + k0 + skoff, &Bs[c0 * 512]);
        gl2lds16(B + (n0 + c1 * 16 + srow) * (long)Kc + k0 + skoff, &Bs[c1 * 512]);
        __syncthreads();

        bf16x8 af[4], bfr[4];
#pragma unroll
        for (int t = 0; t < 4; ++t) {
            af[t]  = *(const bf16x8*)&As[(wm * 64 + t * 16 + mr) * 32 + kq];
            bfr[t] = *(const bf16x8*)&Bs[(wn * 64 + t * 16 + mr) * 32 + kq];
        }
#pragma unroll
        for (int i = 0; i < 4; ++i)
#pragma unroll
            for (int j = 0; j < 4; ++j)
                acc[i][j] = __builtin_amdgcn_mfma_f32_16x16x32_bf16(
                    af[i], bfr[j], acc[i][j], 0, 0, 0);
        __syncthreads();
    }

    const int col = lane & 15, rquad = (lane >> 4) * 4;
#pragma unroll
    for (int i = 0; i < 4; ++i) {
        const long mrow = m0 + wm * 64 + i * 16 + rquad;
#pragma unroll
        for (int j = 0; j < 4; ++j) {
            float* p = C + mrow * (long)N + n0 + wn * 64 + j * 16 + col;
#pragma unroll
            for (int r = 0; r < 4; ++r) p[(long)r * N] = acc[i][j][r];
        }
    }
}

// ===========================================================================
// K1 fused: P = H @ W_I (fp32 VALU GEMM) with split epilogue -> Ap.
// ===========================================================================
__global__ __launch_bounds__(256)
void k1_ap(const float* __restrict__ A, const float* __restrict__ B,
           unsigned short* __restrict__ Ap)
{
    __shared__ __align__(16) float Asl[16][132];
    __shared__ __align__(16) float Bsl[16][132];
    const int tid = threadIdx.x;
    const int tx = tid & 15, ty = tid >> 4;
    const long m0 = (long)blockIdx.x * 128;
    const long n0 = (long)blockIdx.y * 128;
    const int Kc = R_DIM, N = R_DIM;

    float acc[8][8];
#pragma unroll
    for (int i = 0; i < 8; ++i)
#pragma unroll
        for (int j = 0; j < 8; ++j) acc[i][j] = 0.f;

    for (int k0 = 0; k0 < Kc; k0 += 16) {
#pragma unroll
        for (int q = 0; q < 2; ++q) {
            int fi = tid + 256 * q, row = fi >> 2, col = (fi & 3) * 4;
            float4 v = *(const float4*)(A + (m0 + row) * (long)Kc + k0 + col);
            Asl[col + 0][row] = v.x; Asl[col + 1][row] = v.y;
            Asl[col + 2][row] = v.z; Asl[col + 3][row] = v.w;
        }
#pragma unroll
        for (int q = 0; q < 2; ++q) {
            int fi = tid + 256 * q, row = fi >> 5, col = (fi & 31) * 4;
            float4 v = *(const float4*)(B + (k0 + row) * (long)N + n0 + col);
            *(float4*)&Bsl[row][col] = v;
        }
        __syncthreads();
#pragma unroll
        for (int kk = 0; kk < 16; ++kk) {
            float a[8], b[8];
            *(float4*)&a[0] = *(const float4*)&Asl[kk][ty * 8];
            *(float4*)&a[4] = *(const float4*)&Asl[kk][ty * 8 + 4];
            *(float4*)&b[0] = *(const float4*)&Bsl[kk][tx * 8];
            *(float4*)&b[4] = *(const float4*)&Bsl[kk][tx * 8 + 4];
#pragma unroll
            for (int i = 0; i < 8; ++i)
#pragma unroll
                for (int j = 0; j < 8; ++j)
                    acc[i][j] = fmaf(a[i], b[j], acc[i][j]);
        }
        __syncthreads();
    }
#pragma unroll
    for (int i = 0; i < 8; ++i) {
        const long row = m0 + ty * 8 + i;
        u16x8 hi8, lo8;
#pragma unroll
        for (int j = 0; j < 8; ++j) {
            const unsigned short h = f2bf(acc[i][j]);
            hi8[j] = h;
            lo8[j] = f2bf(acc[i][j] - bf2f(h));
        }
        unsigned short* p = Ap + row * KP + n0 + tx * 8;
        *(u16x8*)(p)              = hi8;
        *(u16x8*)(p + R_DIM)      = hi8;
        *(u16x8*)(p + 2 * R_DIM)  = lo8;
    }
}

// ===========================================================================
// T1: per-row softmax stats, two-pass (chain-free).
// 32 rows/block, 8 threads/row. Pass 1: max (4 indep accumulators).
// Pass 2: sum exp (known max; independent exps, L2-hot re-read).
// ===========================================================================
__global__ __launch_bounds__(256)
void row_stats(const float* __restrict__ Mio,
               float* __restrict__ rowM, float* __restrict__ rowInv)
{
    __shared__ float sm[32][8];
    __shared__ float ss[32][8];

    const int tid = threadIdx.x;
    const int arow = tid >> 3, alane = tid & 7;
    const long row = (long)blockIdx.x * 32 + arow;
    const float* rp = Mio + row * (long)K_DIM + alane * 4;

    // pass 1: max
    float4 mx = make_float4(-3.4e38f, -3.4e38f, -3.4e38f, -3.4e38f);
#pragma unroll 8
    for (int q = 0; q < 128; ++q) {
        float4 v = *(const float4*)(rp + 32 * q);
        mx.x = fmaxf(mx.x, v.x); mx.y = fmaxf(mx.y, v.y);
        mx.z = fmaxf(mx.z, v.z); mx.w = fmaxf(mx.w, v.w);
    }
    sm[arow][alane] = fmaxf(fmaxf(mx.x, mx.y), fmaxf(mx.z, mx.w));
    __syncthreads();
    float m = sm[arow][0];
#pragma unroll
    for (int t = 1; t < 8; ++t) m = fmaxf(m, sm[arow][t]);

    // pass 2: sum exp (re-read; strip is L2-resident)
    float4 sx = make_float4(0.f, 0.f, 0.f, 0.f);
#pragma unroll 8
    for (int q = 0; q < 128; ++q) {
        float4 v = *(const float4*)(rp + 32 * q);
        sx.x += __expf(v.x - m); sx.y += __expf(v.y - m);
        sx.z += __expf(v.z - m); sx.w += __expf(v.w - m);
    }
    ss[arow][alane] = (sx.x + sx.y) + (sx.z + sx.w);
    __syncthreads();
    if (alane == 0) {
        float S = 0.f;
#pragma unroll
        for (int t = 0; t < 8; ++t) S += ss[arow][t];
        rowM[row] = m;
        rowInv[row] = 1.f / S;
    }
}

// ===========================================================================
// T2: C = softmax(M) @ L. K2-shaped loop: 64x256 tile, BK=32, 4 waves
// (each wave: 64 rows x 64 cols). A staged from fp32 M with exp applied
// (and fp32 A written back to Mio = the A_I output). B = LT via async DMA.
// ===========================================================================
__global__ __launch_bounds__(256)
void gemm_aw(float* __restrict__ Mio, const unsigned short* __restrict__ LT,
             const float* __restrict__ rowM, const float* __restrict__ rowInv,
             float* __restrict__ C)
{
    __shared__ __align__(16) unsigned short As[64 * 32];
    __shared__ __align__(16) unsigned short Bs[256 * 32];

    const int tid = threadIdx.x, wave = tid >> 6, lane = tid & 63;
    const long m0 = (long)blockIdx.x * 64;

    // A staging: thread t owns row t>>2 (0..63), k-offset (t&3)*8
    const int arow = tid >> 2, akoff = (tid & 3) * 8;
    const float rm = rowM[m0 + arow];
    const float ri = rowInv[m0 + arow];
    float* Ar = Mio + (m0 + arow) * (long)K_DIM + akoff;

    // B staging: 16 chunks (16 rows x 32 k); wave stages chunks wave*4..+3
    const int srow = lane >> 2, skoff = (lane & 3) * 8;
    const int fr = lane & 15, kq = (lane >> 4) * 8;

    f32x4 acc[4][4] = {};   // 4 row-tiles x 4 col-tiles (wave cols = wave*64)

    for (int k0 = 0; k0 < K_DIM; k0 += 32) {
#pragma unroll
        for (int c4 = 0; c4 < 4; ++c4) {
            const int c = wave * 4 + c4;
            gl2lds16(LT + (c * 16 + srow) * (long)K_DIM + k0 + skoff,
                     &Bs[c * 512]);
        }
        {
            float4 v0 = *(const float4*)(Ar + k0);
            float4 v1 = *(const float4*)(Ar + k0 + 4);
            float e[8];
            e[0] = __expf(v0.x - rm) * ri; e[1] = __expf(v0.y - rm) * ri;
            e[2] = __expf(v0.z - rm) * ri; e[3] = __expf(v0.w - rm) * ri;
            e[4] = __expf(v1.x - rm) * ri; e[5] = __expf(v1.y - rm) * ri;
            e[6] = __expf(v1.z - rm) * ri; e[7] = __expf(v1.w - rm) * ri;
            *(float4*)(Ar + k0)     = make_float4(e[0], e[1], e[2], e[3]);
            *(float4*)(Ar + k0 + 4) = make_float4(e[4], e[5], e[6], e[7]);
            u16x8 u;
#pragma unroll
            for (int j = 0; j < 8; ++j) u[j] = f2bf(e[j]);
            *(u16x8*)&As[arow * 32 + akoff] = u;
        }
        __syncthreads();

        bf16x8 af[4], bfr[4];
#pragma unroll
        for (int i = 0; i < 4; ++i)
            af[i] = *(const bf16x8*)&As[(i * 16 + fr) * 32 + kq];
#pragma unroll
        for (int j = 0; j < 4; ++j)
            bfr[j] = *(const bf16x8*)&Bs[(wave * 64 + j * 16 + fr) * 32 + kq];
#pragma unroll
        for (int i = 0; i < 4; ++i)
#pragma unroll
            for (int j = 0; j < 4; ++j)
                acc[i][j] = __builtin_amdgcn_mfma_f32_16x16x32_bf16(
                    af[i], bfr[j], acc[i][j], 0, 0, 0);
        __syncthreads();
    }

    const int col = lane & 15, rq = (lane >> 4) * 4;
#pragma unroll
    for (int i = 0; i < 4; ++i)
#pragma unroll
        for (int j = 0; j < 4; ++j)
#pragma unroll
            for (int r = 0; r < 4; ++r)
                C[(m0 + i * 16 + rq + r) * (long)R_DIM + wave * 64 + j * 16 + col]
                    = acc[i][j][r];
}

// ===========================================================================
// Prep kernels (L-derived operands)
// ===========================================================================
__global__ __launch_bounds__(256)
void prep_B(const float* __restrict__ L, unsigned short* __restrict__ Bp)
{
    const long i = (long)blockIdx.x * 256 + threadIdx.x;
    const long k = i >> 8; const int r = (int)(i & 255);
    const float x = L[i];
    const unsigned short hi = f2bf(x);
    const unsigned short lo = f2bf(x - bf2f(hi));
    unsigned short* row = Bp + k * KP;
    row[r] = hi; row[R_DIM + r] = lo; row[2 * R_DIM + r] = hi;
}

// LDS-tile transpose: LT[r][k] = bf16(L[k][r]); coalesced both sides.
__global__ __launch_bounds__(256)
void prep_LT(const float* __restrict__ L, unsigned short* __restrict__ LT)
{
    __shared__ unsigned short t[64][66];
    const int k0 = blockIdx.x * 64;
    const int r0 = blockIdx.y * 64;
    const int tid = threadIdx.x;
#pragma unroll
    for (int q = 0; q < 16; ++q) {
        const int e = q * 256 + tid;
        const int kk = e >> 6, rr = e & 63;
        t[rr][kk] = f2bf(L[(long)(k0 + kk) * R_DIM + r0 + rr]);
    }
    __syncthreads();
#pragma unroll
    for (int q = 0; q < 16; ++q) {
        const int e = q * 256 + tid;
        const int rr = e >> 6, kk = e & 63;
        LT[(long)(r0 + rr) * K_DIM + k0 + kk] = t[rr][kk];
    }
}

// ===========================================================================
// Fallback kernels (fp32 path, no workspace)
// ===========================================================================
template<bool BT>
__global__ __launch_bounds__(256)
void gemm128(const float* __restrict__ A, const float* __restrict__ B,
             float* __restrict__ C, int M, int N, int Kc)
{
    __shared__ __align__(16) float Asl[16][132];
    __shared__ __align__(16) float Bsl[16][132];
    const int tid = threadIdx.x;
    const int tx = tid & 15, ty = tid >> 4;
    const long m0 = (long)blockIdx.x * 128;
    const long n0 = (long)blockIdx.y * 128;
    float acc[8][8];
#pragma unroll
    for (int i = 0; i < 8; ++i)
#pragma unroll
        for (int j = 0; j < 8; ++j) acc[i][j] = 0.f;
    for (int k0 = 0; k0 < Kc; k0 += 16) {
#pragma unroll
        for (int q = 0; q < 2; ++q) {
            int fi = tid + 256 * q, row = fi >> 2, col = (fi & 3) * 4;
            float4 v = *(const float4*)(A + (m0 + row) * (long)Kc + k0 + col);
            Asl[col + 0][row] = v.x; Asl[col + 1][row] = v.y;
            Asl[col + 2][row] = v.z; Asl[col + 3][row] = v.w;
        }
        if (BT) {
#pragma unroll
            for (int q = 0; q < 2; ++q) {
                int fi = tid + 256 * q, row = fi >> 2, col = (fi & 3) * 4;
                float4 v = *(const float4*)(B + (n0 + row) * (long)Kc + k0 + col);
                Bsl[col + 0][row] = v.x; Bsl[col + 1][row] = v.y;
                Bsl[col + 2][row] = v.z; Bsl[col + 3][row] = v.w;
            }
        } else {
#pragma unroll
            for (int q = 0; q < 2; ++q) {
                int fi = tid + 256 * q, row = fi >> 5, col = (fi & 31) * 4;
                float4 v = *(const float4*)(B + (k0 + row) * (long)N + n0 + col);
                *(float4*)&Bsl[row][col] = v;
            }
        }
        __syncthreads();
#pragma unroll
        for (int kk = 0; kk < 16; ++kk) {
            float a[8], b[8];
            *(float4*)&a[0] = *(const float4*)&Asl[kk][ty * 8];
            *(float4*)&a[4] = *(const float4*)&Asl[kk][ty * 8 + 4];
            *(float4*)&b[0] = *(const float4*)&Bsl[kk][tx * 8];
            *(float4*)&b[4] = *(const float4*)&Bsl[kk][tx * 8 + 4];
#pragma unroll
            for (int i = 0; i < 8; ++i)
#pragma unroll
                for (int j = 0; j < 8; ++j)
                    acc[i][j] = fmaf(a[i], b[j], acc[i][j]);
        }
        __syncthreads();
    }
#pragma unroll
    for (int i = 0; i < 8; ++i) {
        float* p = C + (m0 + ty * 8 + i) * (long)N + n0 + tx * 8;
        *(float4*)p       = make_float4(acc[i][0], acc[i][1], acc[i][2], acc[i][3]);
        *(float4*)(p + 4) = make_float4(acc[i][4], acc[i][5], acc[i][6], acc[i][7]);
    }
}

__global__ __launch_bounds__(256)
void softmax_rows(float* __restrict__ Mio)
{
    const long n  = blockIdx.x;
    float* row    = Mio + n * (long)K_DIM;
    const int tid = threadIdx.x;
    float4 v[4];
    float lmax = -3.4e38f;
#pragma unroll
    for (int q = 0; q < 4; ++q) {
        v[q] = ((const float4*)row)[tid + 256 * q];
        lmax = fmaxf(lmax, fmaxf(fmaxf(v[q].x, v[q].y), fmaxf(v[q].z, v[q].w)));
    }
    __shared__ float redmax[4], redsum[4];
#pragma unroll
    for (int off = 32; off > 0; off >>= 1)
        lmax = fmaxf(lmax, __shfl_xor(lmax, off));
    if ((tid & 63) == 0) redmax[tid >> 6] = lmax;
    __syncthreads();
    const float gmax = fmaxf(fmaxf(redmax[0], redmax[1]), fmaxf(redmax[2], redmax[3]));
    float lsum = 0.f;
#pragma unroll
    for (int q = 0; q < 4; ++q) {
        v[q].x = __expf(v[q].x - gmax); v[q].y = __expf(v[q].y - gmax);
        v[q].z = __expf(v[q].z - gmax); v[q].w = __expf(v[q].w - gmax);
        lsum += v[q].x + v[q].y + v[q].z + v[q].w;
    }
#pragma unroll
    for (int off = 32; off > 0; off >>= 1)
        lsum += __shfl_xor(lsum, off);
    if ((tid & 63) == 0) redsum[tid >> 6] = lsum;
    __syncthreads();
    const float inv = 1.f / (redsum[0] + redsum[1] + redsum[2] + redsum[3]);
#pragma unroll
    for (int q = 0; q < 4; ++q) {
        v[q].x *= inv; v[q].y *= inv; v[q].z *= inv; v[q].w *= inv;
        ((float4*)row)[tid + 256 * q] = v[q];
    }
}

// ===========================================================================
extern "C" void kernel_launch(void* const* d_in, const int* in_sizes, int n_in,
                              void* d_out, int out_size, void* d_ws, size_t ws_size,
                              hipStream_t stream)
{
    const float* H  = (const float*)d_in[0];
    const float* L  = (const float*)d_in[1];
    const float* Wi = (const float*)d_in[2];

    float* Cout = (float*)d_out;                           // N x R
    float* Aout = (float*)d_out + (size_t)N_ROWS * R_DIM;  // N x K

    const size_t szAp = (size_t)N_ROWS * KP * 2;     // 48 MiB
    const size_t szBp = (size_t)K_DIM * KP * 2;      //  6 MiB
    const size_t szLT = (size_t)R_DIM * K_DIM * 2;   //  2 MiB
    const size_t szRM = (size_t)N_ROWS * 4;          //  128 KiB

    if (ws_size >= szAp + szBp + szLT + 2 * szRM) {
        char* w = (char*)d_ws;
        unsigned short* Ap = (unsigned short*)w;  w += szAp;
        unsigned short* Bp = (unsigned short*)w;  w += szBp;
        unsigned short* LT = (unsigned short*)w;  w += szLT;
        float* rowM   = (float*)w;                w += szRM;
        float* rowInv = (float*)w;

        // K1 fused: P = H@W_I with split-epilogue -> Ap
        k1_ap<<<dim3(N_ROWS / 128, R_DIM / 128), 256, 0, stream>>>(H, Wi, Ap);
        // L-derived operands
        prep_B<<<dim3((K_DIM * R_DIM) / 256), 256, 0, stream>>>(L, Bp);
        prep_LT<<<dim3(K_DIM / 64, R_DIM / 64), 256, 0, stream>>>(L, LT);
        // K2: logits M
        gemm_mfma_nt<<<dim3(K_DIM / 128, N_ROWS / 128), 256, 0, stream>>>(
            Ap, Bp, Aout, N_ROWS, K_DIM, KP);
        // T1: row stats (two-pass, chain-free)
        row_stats<<<dim3(N_ROWS / 32), 256, 0, stream>>>(Aout, rowM, rowInv);
        // T2: A written in place + C = A@L (K2-shaped MFMA loop)
        gemm_aw<<<dim3(N_ROWS / 64), 256, 0, stream>>>(
            Aout, LT, rowM, rowInv, Cout);
    } else {
        gemm128<false><<<dim3(N_ROWS / 128, R_DIM / 128), 256, 0, stream>>>(
            H, Wi, Cout, N_ROWS, R_DIM, R_DIM);
        gemm128<true><<<dim3(N_ROWS / 128, K_DIM / 128), 256, 0, stream>>>(
            Cout, L, Aout, N_ROWS, K_DIM, R_DIM);
        softmax_rows<<<dim3(N_ROWS), 256, 0, stream>>>(Aout);
        gemm128<false><<<dim3(N_ROWS / 128, R_DIM / 128), 256, 0, stream>>>(
            Aout, L, Cout, N_ROWS, R_DIM, K_DIM);
    }
}